// Round 3
// baseline (1735.886 us; speedup 1.0000x reference)
//
#include <hip/hip_runtime.h>
#include <math.h>

// Problem constants (from reference)
#define B_   8
#define T_   128
#define E_   256
#define H_   512
#define G_   2048          // 4*H
#define NWG  256           // 1 WG per CU -> co-resident
#define NTHR 256
#define WPITCH 516         // LDS pitch for weight slice (512+4): b128 dot reads at bandwidth floor
#define HPITCH 516         // LDS pitch for staged h
#define XPITCH 1025        // LDS pitch for column-major X (conflict-free)

typedef unsigned long long u64;

// ---------------------------------------------------------------------------
// ALGEBRAIC SIMPLIFICATION (verified against reference math):
//  softmax(Si) sums to 1 over t and h_shared = h_last[:,None,:] is t-invariant,
//  so Rt == h_last ALWAYS. Attention path (Ws_w/Ws_b/Us_w/Us_b, softmax) and
//  shared_out are dead. Remaining:
//    h_last = sharedLSTM(emb); M = h_last @ Wmh_t (step-invariant);
//    out = taskLSTM(emb; pre = X2[t] + h@Whh_t + M)
//
// R3: ZERO grid barriers. h exchange is self-validating: each exchanged fp32
// has its mantissa LSB set to parity (gen>>1)&1; records are double-buffered
// by gen&1. Consumers poll their record's 8 u64 words until all LSBs match —
// data arrives WITH the successful poll (1 MALL hop). Producers fire 8
// independent relaxed agent-scope u64 stores (no drain/ordering needed).
// Safety: gen g+2 is only written after its writer consumed g+1, which
// requires ALL WGs to have produced g+1, which requires ALL WGs to have
// finished consuming g -> no consumer can be lapped; stale = g-2 = opposite
// parity. Gen g lives in buffer g&1; parity (g>>1)&1 differs from g-2's. t=0
// steps skip the exchange (h=0 -> dot=0).
// ---------------------------------------------------------------------------

__device__ __forceinline__ float sigf(float x) { return 1.0f / (1.0f + expf(-x)); }

// recs[gen&1][wg][b] : u64 = {hi = h[b][2wg+1], lo = h[b][2wg]} (LSB-tagged)
__global__ void init_ws(u64* recs) {
  int i = blockIdx.x * blockDim.x + threadIdx.x;     // 2*256*8 = 4096 words
  if (i < 2 * NWG * B_)
    // buffer0: LSB=0 (first read is gen2, parity 1 -> rejected)
    // buffer1: LSB=1 (first read is gen1, parity 0 -> rejected until written)
    recs[i] = (i < NWG * B_) ? 0ull : 0x0000000100000001ull;
}

// Poll record `threadIdx.x` of generation `gen` until valid, then stage the
// 16 floats (cols 2r,2r+1 x 8 batches) into h_lds. b64 LDS writes: 4-way.
__device__ __forceinline__ void poll_stage(const u64* __restrict__ recs,
                                           unsigned gen, float* h_lds) {
  const int r = threadIdx.x;
  const u64* rec = recs + ((gen & 1u) * NWG + (unsigned)r) * B_;
  const unsigned p = (gen >> 1) & 1u;
  u64 v[B_];
  for (;;) {
    unsigned bad = 0;
#pragma unroll
    for (int j = 0; j < B_; ++j)
      v[j] = __hip_atomic_load(rec + j, __ATOMIC_RELAXED, __HIP_MEMORY_SCOPE_AGENT);
#pragma unroll
    for (int j = 0; j < B_; ++j)
      bad |= ((unsigned)v[j] ^ p) | (((unsigned)(v[j] >> 32)) ^ p);
    if (!(bad & 1u)) break;
    __builtin_amdgcn_s_sleep(1);
  }
#pragma unroll
  for (int j = 0; j < B_; ++j)
    *(u64*)(h_lds + j * HPITCH + 2 * r) = v[j];
}

// Load a 512x8 column-slice of a (512 x 2048) recurrent weight into LDS.
// Columns for this WG: col(c) = (c>>1)*H + wg*2 + (c&1)  (4 gates x 2 h-cols)
__device__ __forceinline__ void load_wslice(const float* __restrict__ W, int wg, float* Wl) {
  for (int idx = threadIdx.x; idx < H_ * 8; idx += NTHR) {
    int k = idx >> 3, c = idx & 7;
    Wl[c * WPITCH + k] = W[k * G_ + ((c >> 1) * H_ + wg * 2 + (c & 1))];
  }
}

// One (b, ci) dot over a K-quarter (both operands LDS), reduced across the 4
// k-quarter lanes. Returns the FULL dot on every participating lane.
__device__ __forceinline__ float dot_lds(const float* __restrict__ h_lds,
                                         const float* __restrict__ Wl,
                                         int b, int ci, int q) {
  const float4* h4 = (const float4*)(h_lds + b * HPITCH + q * 128);
  const float4* w4 = (const float4*)(Wl + ci * WPITCH + q * 128);
  float s0 = 0.f, s1 = 0.f, s2 = 0.f, s3 = 0.f;
#pragma unroll 8
  for (int i = 0; i < 32; ++i) {
    float4 hv = h4[i];
    float4 wv = w4[i];
    s0 += hv.x * wv.x; s1 += hv.y * wv.y; s2 += hv.z * wv.z; s3 += hv.w * wv.w;
  }
  float s = (s0 + s1) + (s2 + s3);
  s += __shfl_xor(s, 8);    // reduce over q (tid bits 3..4 are lane bits 3..4)
  s += __shfl_xor(s, 16);
  return s;
}

// X[c][r] = sum_e emb[r][e]*Wih[e][col(c)] + bias[col(c)], r = t*8+b, col-major.
__device__ __forceinline__ void compute_X(const float* __restrict__ Wih,
                                          const float* __restrict__ bias,
                                          const int* __restrict__ tokens,
                                          const float* __restrict__ embed,
                                          int wg, float* Wbuf, float* Xlds,
                                          float* bias_lds) {
  const int tid = threadIdx.x;
  for (int idx = tid; idx < E_ * 8; idx += NTHR) {
    int e = idx >> 3, c = idx & 7;
    Wbuf[idx] = Wih[e * G_ + ((c >> 1) * H_ + wg * 2 + (c & 1))];
  }
  if (tid < 8) bias_lds[tid] = bias[(tid >> 1) * H_ + wg * 2 + (tid & 1)];
  __syncthreads();

  const float4* er[4];
#pragma unroll
  for (int rr = 0; rr < 4; ++rr) {
    int r = tid + rr * NTHR;
    int tok = tokens[(r & 7) * T_ + (r >> 3)];   // tokens is (B,T); r = t*8+b
    er[rr] = (const float4*)(embed + (size_t)tok * E_);
  }
  float acc[4][8];
#pragma unroll
  for (int rr = 0; rr < 4; ++rr)
#pragma unroll
    for (int c = 0; c < 8; ++c) acc[rr][c] = bias_lds[c];

  for (int ec = 0; ec < E_ / 4; ++ec) {
    float4 ev[4];
#pragma unroll
    for (int rr = 0; rr < 4; ++rr) ev[rr] = er[rr][ec];
    float4 wv[8];
    const float4* w4 = (const float4*)(Wbuf + ec * 32);
#pragma unroll
    for (int u = 0; u < 8; ++u) wv[u] = w4[u];   // broadcast LDS reads
    const float* w = reinterpret_cast<const float*>(&wv[0]);
#pragma unroll
    for (int eo = 0; eo < 4; ++eo) {
#pragma unroll
      for (int c = 0; c < 8; ++c) {
        float wf = w[eo * 8 + c];
#pragma unroll
        for (int rr = 0; rr < 4; ++rr)
          acc[rr][c] += reinterpret_cast<const float*>(&ev[rr])[eo] * wf;
      }
    }
  }
#pragma unroll
  for (int rr = 0; rr < 4; ++rr) {
    int r = tid + rr * NTHR;
#pragma unroll
    for (int c = 0; c < 8; ++c)
      Xlds[c * XPITCH + r] = acc[rr][c];   // col-major: conflict-free writes
  }
}

__global__ __launch_bounds__(NTHR, 1) void lstm_all(
    const int* __restrict__ tokens, const float* __restrict__ embed,
    const float* __restrict__ Wih_s, const float* __restrict__ Whh_s,
    const float* __restrict__ b_s,
    const float* __restrict__ Wih_t, const float* __restrict__ Whh_t,
    const float* __restrict__ Wmh_t, const float* __restrict__ b_t,
    float* __restrict__ out, u64* __restrict__ recs) {
  __shared__ float Wlds[8 * WPITCH];     // 16.5 KB (also Wih staging)
  __shared__ float h_lds[8 * HPITCH];    // 16.5 KB staged h
  __shared__ float Xlds[8 * XPITCH];     // 32.8 KB X slice (col-major)
  __shared__ float pre_lds[64];
  __shared__ float M_lds[64];
  __shared__ float c_lds[16];
  __shared__ float bias_lds[8];

  const int tid = threadIdx.x;
  const int wg  = blockIdx.x;

  const int ci = tid & 7;          // owned column index within slice
  const int q  = (tid >> 3) & 3;   // k-quarter
  const int b  = tid >> 5;         // batch

  // ---------------- Phase A1: X1 = emb @ Wih_s + b_s (per-WG slice, LDS)
  compute_X(Wih_s, b_s, tokens, embed, wg, Wlds, Xlds, bias_lds);
  __syncthreads();

  load_wslice(Whh_s, wg, Wlds);
  if (tid < 16) c_lds[tid] = 0.0f;
  __syncthreads();

  // ---------------- Phase B: shared LSTM (only h_last is live)
  for (int t = 0; t < T_; ++t) {
    float d = 0.0f;
    if (t > 0) {                             // t==0: h=0 -> dot=0, no exchange
      poll_stage(recs, (unsigned)t, h_lds);  // read gen t
      __syncthreads();                       // staging done; also protects prior pre/gates
      d = dot_lds(h_lds, Wlds, b, ci, q);
    }
    if (q == 0) pre_lds[b * 8 + ci] = d + Xlds[ci * XPITCH + t * 8 + b];
    __syncthreads();
    if (tid < 16) {
      int bb = tid >> 1, jj = tid & 1;
      float pi = pre_lds[bb * 8 + 0 + jj];
      float pf = pre_lds[bb * 8 + 2 + jj];
      float pg = pre_lds[bb * 8 + 4 + jj];
      float po = pre_lds[bb * 8 + 6 + jj];
      float cc = c_lds[tid];
      float cn = sigf(pf) * cc + sigf(pi) * tanhf(pg);
      float hn = sigf(po) * tanhf(cn);
      c_lds[tid] = cn;
      const unsigned gw = (unsigned)t + 1u;            // write gen t+1
      const unsigned pn = (gw >> 1) & 1u;
      unsigned hb = (__float_as_uint(hn) & ~1u) | pn;  // LSB = parity tag
      unsigned ob = (unsigned)__shfl_xor((int)hb, 1);  // partner (jj^1) value
      if (jj == 0) {
        u64 w = ((u64)ob << 32) | (u64)hb;
        __hip_atomic_store(recs + ((gw & 1u) * NWG + wg) * B_ + bb, w,
                           __ATOMIC_RELAXED, __HIP_MEMORY_SCOPE_AGENT);
      }
    }
    // no barrier: next poll_stage IS the synchronization
  }

  // ---------------- M = h_last @ Wmh_t (attention collapses to this); gen 128
  load_wslice(Wmh_t, wg, Wlds);     // Wlds safe: last dot synced at t=127
  poll_stage(recs, 128u, h_lds);
  __syncthreads();
  {
    float dm = dot_lds(h_lds, Wlds, b, ci, q);
    if (q == 0) M_lds[b * 8 + ci] = dm;
  }
  __syncthreads();

  // ---------------- Phase A2: X2 = emb @ Wih_t + b_t
  compute_X(Wih_t, b_t, tokens, embed, wg, Wlds, Xlds, bias_lds);
  __syncthreads();

  load_wslice(Whh_t, wg, Wlds);
  if (tid < 16) c_lds[tid] = 0.0f;
  __syncthreads();

  // ---------------- Phase C: task LSTM, writes output every step
  for (int t = 0; t < T_; ++t) {
    float d = 0.0f;
    if (t > 0) {
      poll_stage(recs, 128u + (unsigned)t, h_lds);   // read gen 128+t
      __syncthreads();
      d = dot_lds(h_lds, Wlds, b, ci, q);
    }
    if (q == 0)
      pre_lds[b * 8 + ci] = d + Xlds[ci * XPITCH + t * 8 + b] + M_lds[b * 8 + ci];
    __syncthreads();
    if (tid < 16) {
      int bb = tid >> 1, jj = tid & 1;
      float pi = pre_lds[bb * 8 + 0 + jj];
      float pf = pre_lds[bb * 8 + 2 + jj];
      float pg = pre_lds[bb * 8 + 4 + jj];
      float po = pre_lds[bb * 8 + 6 + jj];
      float cc = c_lds[tid];
      float cn = sigf(pf) * cc + sigf(pi) * tanhf(pg);
      float hn = sigf(po) * tanhf(cn);
      c_lds[tid] = cn;
      out[bb * (T_ * H_) + t * H_ + wg * 2 + jj] = hn;
      if (t < T_ - 1) {                                // gen 256 never read
        const unsigned gw = 129u + (unsigned)t;        // write gen 129+t
        const unsigned pn = (gw >> 1) & 1u;
        unsigned hb = (__float_as_uint(hn) & ~1u) | pn;
        unsigned ob = (unsigned)__shfl_xor((int)hb, 1);
        if (jj == 0) {
          u64 w = ((u64)ob << 32) | (u64)hb;
          __hip_atomic_store(recs + ((gw & 1u) * NWG + wg) * B_ + bb, w,
                             __ATOMIC_RELAXED, __HIP_MEMORY_SCOPE_AGENT);
        }
      }
    }
  }
}

extern "C" void kernel_launch(void* const* d_in, const int* in_sizes, int n_in,
                              void* d_out, int out_size, void* d_ws, size_t ws_size,
                              hipStream_t stream) {
  const int*   tokens = (const int*)d_in[0];
  // d_in[1] = TASK (unused)
  const float* embed  = (const float*)d_in[2];
  const float* Wih_s  = (const float*)d_in[3];
  const float* Whh_s  = (const float*)d_in[4];
  const float* b_s    = (const float*)d_in[5];
  // d_in[6..9] = Ws_w, Ws_b, Us_w, Us_b -> dead code (attention collapses)
  const float* Wih_t  = (const float*)d_in[10];
  const float* Whh_t  = (const float*)d_in[11];
  const float* Wmh_t  = (const float*)d_in[12];
  const float* b_t    = (const float*)d_in[13];
  float* out = (float*)d_out;
  u64*   recs = (u64*)d_ws;

  hipLaunchKernelGGL(init_ws, dim3(16), dim3(NTHR), 0, stream, recs);
  hipLaunchKernelGGL(lstm_all, dim3(NWG), dim3(NTHR), 0, stream,
                     tokens, embed, Wih_s, Whh_s, b_s,
                     Wih_t, Whh_t, Wmh_t, b_t, out, recs);
}

// Round 4
// 1518.760 us; speedup vs baseline: 1.1430x; 1.1430x over previous
//
#include <hip/hip_runtime.h>
#include <math.h>

// Problem constants (from reference)
#define B_   8
#define T_   128
#define E_   256
#define H_   512
#define G_   2048          // 4*H
#define NWG  128           // 1 WG per CU, co-resident (128 <= 256 CUs)
#define NTHR 512
#define NCOL 4             // h-columns owned per WG  (128*4 = 512 = H)
#define NGC  16            // gate columns per WG (4 gates x NCOL)
#define WPITCH 516         // LDS pitch, weight slice rows
#define HPITCH 516         // LDS pitch, staged h rows (mult of 4 -> float4 ok)
#define XPITCH 1025        // LDS pitch, column-major X (conflict-free)

typedef unsigned long long u64;

// ---------------------------------------------------------------------------
// ALGEBRA (unchanged): softmax sums to 1 over t and h_shared is t-invariant =>
// Rt == h_last; attention path is dead. Compute:
//   h_last = sharedLSTM(emb); M = h_last @ Wmh_t; out = taskLSTM(emb; X2+h@Whh_t+M)
//
// R4 sync: per-producer MONOTONIC FLAG + one-shot payload read.
//  ws layout (floats): recs[2][4096] data (recs[p][w*32 + b*4 + j] = h[b][w*4+j]),
//  then unsigned flags[128] at float offset 8192. flags[w] = g  <=>  WG w has
//  published gen g into buffer g&1. Producer: relaxed agent data stores ->
//  s_waitcnt vmcnt(0) -> relaxed flag store (no cache-maintenance fences!).
//  Consumer thread polls ONE 4B flag (wave-coalesced to one 64B line), then
//  reads its 32B payload slice once. No-overwrite proof: writing gen g+2
//  requires consuming g+1 from ALL => all produced g+1 => all finished
//  reading g. Poll traffic/round: 128 WG * 2KB = 0.25 MB (R3: 4 MB -> MALL
//  saturation, the measured 6.5us/step).
// ---------------------------------------------------------------------------

__device__ __forceinline__ float sigf(float x) { return 1.0f / (1.0f + expf(-x)); }

__global__ void init_ws(float* ws) {
  unsigned* flags = (unsigned*)(ws + 8192);
  int i = blockIdx.x * blockDim.x + threadIdx.x;
  if (i < NWG) flags[i] = 0u;
}

// Poll own flag, then read 8 floats of payload and stage into h_lds.
// thread i -> producer w = i>>2, floats [i*8, i*8+8) of the 4096-float image.
__device__ __forceinline__ void poll_read_stage(const float* __restrict__ ws,
                                                unsigned gen, float* __restrict__ h_lds) {
  const int i = threadIdx.x;
  const unsigned* flags = (const unsigned*)(ws + 8192);
  while (__hip_atomic_load(&flags[i >> 2], __ATOMIC_RELAXED,
                           __HIP_MEMORY_SCOPE_AGENT) < gen)
    __builtin_amdgcn_s_sleep(1);
  const u64* src = (const u64*)(ws + (gen & 1u) * 4096) + (size_t)i * 4;
  u64 v[4];
#pragma unroll
  for (int j = 0; j < 4; ++j)
    v[j] = __hip_atomic_load(src + j, __ATOMIC_RELAXED, __HIP_MEMORY_SCOPE_AGENT);
  // float f = i*8+k: w = f>>5, bb = (f&31)>>2, jj = f&3 -> h_lds[bb][w*4+jj]
  const int w   = i >> 2;
  const int bb0 = (i & 3) * 2;
  union { u64 u[2]; float4 f; } a, b;
  a.u[0] = v[0]; a.u[1] = v[1];
  b.u[0] = v[2]; b.u[1] = v[3];
  *(float4*)(h_lds + bb0 * HPITCH + w * 4)       = a.f;   // k=0..3
  *(float4*)(h_lds + (bb0 + 1) * HPITCH + w * 4) = b.f;   // k=4..7
}

// Stage 512x16 column-slice of a (512 x 2048) recurrent weight into LDS.
// col(c) = (c>>2)*H + wg*NCOL + (c&3)   (4 gates x 4 h-cols)
__device__ __forceinline__ void load_wslice(const float* __restrict__ W, int wg,
                                            float* __restrict__ Wl) {
  for (int idx = threadIdx.x; idx < H_ * NGC; idx += NTHR) {
    int k = idx >> 4, c = idx & 15;
    Wl[c * WPITCH + k] = W[k * G_ + ((c >> 2) * H_ + wg * NCOL + (c & 3))];
  }
}

// Dot with register-cached weights; h broadcast-read from LDS (16 c-lanes share
// each address). Reduce over the 4 K-quarter lanes (lane bits 4..5).
__device__ __forceinline__ float dot_h(const float* __restrict__ h_lds,
                                       const float4* __restrict__ wr, int b, int q) {
  const float4* h4 = (const float4*)(h_lds + b * HPITCH + q * 128);
  float s0 = 0.f, s1 = 0.f, s2 = 0.f, s3 = 0.f;
#pragma unroll
  for (int i = 0; i < 32; ++i) {
    float4 hv = h4[i];
    float4 wv = wr[i];
    s0 += hv.x * wv.x; s1 += hv.y * wv.y; s2 += hv.z * wv.z; s3 += hv.w * wv.w;
  }
  float s = (s0 + s1) + (s2 + s3);
  s += __shfl_xor(s, 16);
  s += __shfl_xor(s, 32);
  return s;
}

// X[c][r] = sum_e emb[r][e]*Wih[e][col(c)] + bias[col(c)], r = t*8+b, col-major.
__device__ __forceinline__ void compute_X(const float* __restrict__ Wih,
                                          const float* __restrict__ bias,
                                          const int* __restrict__ tokens,
                                          const float* __restrict__ embed,
                                          int wg, float* __restrict__ Wbuf,
                                          float* __restrict__ Xlds,
                                          float* __restrict__ bias_lds) {
  const int tid = threadIdx.x;
  for (int idx = tid; idx < E_ * NGC; idx += NTHR) {     // 4096
    int e = idx >> 4, c = idx & 15;
    Wbuf[idx] = Wih[e * G_ + ((c >> 2) * H_ + wg * NCOL + (c & 3))];
  }
  if (tid < NGC) bias_lds[tid] = bias[(tid >> 2) * H_ + wg * NCOL + (tid & 3)];
  __syncthreads();

  const float4* er[2];
#pragma unroll
  for (int rr = 0; rr < 2; ++rr) {
    int r = tid + rr * NTHR;
    int tok = tokens[(r & 7) * T_ + (r >> 3)];           // tokens (B,T); r = t*8+b
    er[rr] = (const float4*)(embed + (size_t)tok * E_);
  }
  float acc[2][NGC];
#pragma unroll
  for (int rr = 0; rr < 2; ++rr)
#pragma unroll
    for (int cc = 0; cc < NGC; ++cc) acc[rr][cc] = bias_lds[cc];

  for (int ec = 0; ec < E_ / 4; ++ec) {
    float4 ev[2];
#pragma unroll
    for (int rr = 0; rr < 2; ++rr) ev[rr] = er[rr][ec];
    const float4* w4 = (const float4*)(Wbuf + ec * 64);  // 4 e's x 16 c
#pragma unroll
    for (int eo = 0; eo < 4; ++eo) {
      float wrow[16];
      *(float4*)(wrow + 0)  = w4[eo * 4 + 0];            // broadcast LDS reads
      *(float4*)(wrow + 4)  = w4[eo * 4 + 1];
      *(float4*)(wrow + 8)  = w4[eo * 4 + 2];
      *(float4*)(wrow + 12) = w4[eo * 4 + 3];
#pragma unroll
      for (int cc = 0; cc < NGC; ++cc) {
#pragma unroll
        for (int rr = 0; rr < 2; ++rr)
          acc[rr][cc] += reinterpret_cast<const float*>(&ev[rr])[eo] * wrow[cc];
      }
    }
  }
#pragma unroll
  for (int rr = 0; rr < 2; ++rr) {
    int r = tid + rr * NTHR;
#pragma unroll
    for (int cc = 0; cc < NGC; ++cc)
      Xlds[cc * XPITCH + r] = acc[rr][cc];               // conflict-free writes
  }
}

__global__ __launch_bounds__(NTHR, 1) void lstm_all(
    const int* __restrict__ tokens, const float* __restrict__ embed,
    const float* __restrict__ Wih_s, const float* __restrict__ Whh_s,
    const float* __restrict__ b_s,
    const float* __restrict__ Wih_t, const float* __restrict__ Whh_t,
    const float* __restrict__ Wmh_t, const float* __restrict__ b_t,
    float* __restrict__ out, float* __restrict__ ws) {
  __shared__ float Wlds[NGC * WPITCH];   // 33.0 KB (weight staging)
  __shared__ float Xlds[NGC * XPITCH];   // 65.6 KB col-major X
  __shared__ float h_lds[B_ * HPITCH];   // 16.5 KB staged h (also Wih staging)
  __shared__ float pre_lds[B_ * NGC];
  __shared__ float M_lds[B_ * NGC];
  __shared__ float c_lds[B_ * NCOL];
  __shared__ float bias_lds[NGC];

  const int tid = threadIdx.x;
  const int wg  = blockIdx.x;
  float*    recs  = ws;                       // recs[2][4096]
  unsigned* flags = (unsigned*)(ws + 8192);

  const int c = tid & 15;          // owned gate-col index within slice
  const int q = (tid >> 4) & 3;    // K-quarter (lane bits 4..5)
  const int b = tid >> 6;          // batch (= wave id)

  float4 wr[32];                   // register-cached weight K-slice (128 floats)

  // ---------------- Phase A1: X1 = emb @ Wih_s + b_s
  compute_X(Wih_s, b_s, tokens, embed, wg, h_lds, Xlds, bias_lds);
  __syncthreads();                 // Xlds ready; h_lds (Wih staging) free

  load_wslice(Whh_s, wg, Wlds);
  if (tid < 32) c_lds[tid] = 0.0f;
  __syncthreads();
#pragma unroll
  for (int i = 0; i < 32; ++i)
    wr[i] = *(const float4*)(Wlds + c * WPITCH + q * 128 + i * 4);

  // ---------------- Phase B: shared LSTM (only h_last live)
  for (int t = 0; t < T_; ++t) {
    float d = 0.0f;
    if (t > 0) {
      poll_read_stage(ws, (unsigned)t, h_lds);
      __syncthreads();
      d = dot_h(h_lds, wr, b, q);
    }
    if (q == 0) pre_lds[b * NGC + c] = d + Xlds[c * XPITCH + t * 8 + b];
    __syncthreads();
    if (tid < 64) {                       // wave 0 only (uniform branch)
      if (tid < 32) {
        int bb = tid >> 2, jj = tid & 3;
        float pi = pre_lds[bb * NGC + 0  + jj];
        float pf = pre_lds[bb * NGC + 4  + jj];
        float pg = pre_lds[bb * NGC + 8  + jj];
        float po = pre_lds[bb * NGC + 12 + jj];
        float cc = c_lds[tid];
        float cn = sigf(pf) * cc + sigf(pi) * tanhf(pg);
        float hn = sigf(po) * tanhf(cn);
        c_lds[tid] = cn;
        const unsigned gw = (unsigned)t + 1u;            // publish gen t+1
        __hip_atomic_store(recs + (gw & 1u) * 4096 + wg * 32 + tid, hn,
                           __ATOMIC_RELAXED, __HIP_MEMORY_SCOPE_AGENT);
      }
      __builtin_amdgcn_s_waitcnt(0x0f70);  // vmcnt(0): data stores at coherence pt
      if (tid == 0)
        __hip_atomic_store(&flags[wg], (unsigned)t + 1u,
                           __ATOMIC_RELAXED, __HIP_MEMORY_SCOPE_AGENT);
    }
  }

  // ---------------- M = h_last @ Wmh_t (gen 128)
  load_wslice(Wmh_t, wg, Wlds);
  poll_read_stage(ws, 128u, h_lds);
  __syncthreads();
#pragma unroll
  for (int i = 0; i < 32; ++i)
    wr[i] = *(const float4*)(Wlds + c * WPITCH + q * 128 + i * 4);
  {
    float dm = dot_h(h_lds, wr, b, q);
    if (q == 0) M_lds[b * NGC + c] = dm;
  }
  __syncthreads();

  // ---------------- Phase A2: X2 = emb @ Wih_t + b_t
  compute_X(Wih_t, b_t, tokens, embed, wg, h_lds, Xlds, bias_lds);
  __syncthreads();

  load_wslice(Whh_t, wg, Wlds);
  if (tid < 32) c_lds[tid] = 0.0f;
  __syncthreads();
#pragma unroll
  for (int i = 0; i < 32; ++i)
    wr[i] = *(const float4*)(Wlds + c * WPITCH + q * 128 + i * 4);

  // ---------------- Phase C: task LSTM, writes output every step
  for (int t = 0; t < T_; ++t) {
    float d = 0.0f;
    if (t > 0) {
      poll_read_stage(ws, 128u + (unsigned)t, h_lds);
      __syncthreads();
      d = dot_h(h_lds, wr, b, q);
    }
    if (q == 0)
      pre_lds[b * NGC + c] = d + Xlds[c * XPITCH + t * 8 + b] + M_lds[b * NGC + c];
    __syncthreads();
    if (tid < 64) {
      if (tid < 32) {
        int bb = tid >> 2, jj = tid & 3;
        float pi = pre_lds[bb * NGC + 0  + jj];
        float pf = pre_lds[bb * NGC + 4  + jj];
        float pg = pre_lds[bb * NGC + 8  + jj];
        float po = pre_lds[bb * NGC + 12 + jj];
        float cc = c_lds[tid];
        float cn = sigf(pf) * cc + sigf(pi) * tanhf(pg);
        float hn = sigf(po) * tanhf(cn);
        c_lds[tid] = cn;
        out[bb * (T_ * H_) + t * H_ + wg * NCOL + jj] = hn;
        if (t < T_ - 1) {
          const unsigned gw = 129u + (unsigned)t;        // publish gen 129+t
          __hip_atomic_store(recs + (gw & 1u) * 4096 + wg * 32 + tid, hn,
                             __ATOMIC_RELAXED, __HIP_MEMORY_SCOPE_AGENT);
        }
      }
      __builtin_amdgcn_s_waitcnt(0x0f70);
      if (tid == 0 && t < T_ - 1)
        __hip_atomic_store(&flags[wg], 129u + (unsigned)t,
                           __ATOMIC_RELAXED, __HIP_MEMORY_SCOPE_AGENT);
    }
  }
}

extern "C" void kernel_launch(void* const* d_in, const int* in_sizes, int n_in,
                              void* d_out, int out_size, void* d_ws, size_t ws_size,
                              hipStream_t stream) {
  const int*   tokens = (const int*)d_in[0];
  // d_in[1] = TASK (unused)
  const float* embed  = (const float*)d_in[2];
  const float* Wih_s  = (const float*)d_in[3];
  const float* Whh_s  = (const float*)d_in[4];
  const float* b_s    = (const float*)d_in[5];
  // d_in[6..9] = Ws_w, Ws_b, Us_w, Us_b -> dead (attention collapses)
  const float* Wih_t  = (const float*)d_in[10];
  const float* Whh_t  = (const float*)d_in[11];
  const float* Wmh_t  = (const float*)d_in[12];
  const float* b_t    = (const float*)d_in[13];
  float* out = (float*)d_out;
  float* ws  = (float*)d_ws;

  hipLaunchKernelGGL(init_ws, dim3(1), dim3(NWG), 0, stream, ws);
  hipLaunchKernelGGL(lstm_all, dim3(NWG), dim3(NTHR), 0, stream,
                     tokens, embed, Wih_s, Whh_s, b_s,
                     Wih_t, Whh_t, Wmh_t, b_t, out, ws);
}